// Round 1
// baseline (848.826 us; speedup 1.0000x reference)
//
#include <hip/hip_runtime.h>

// ---------------------------------------------------------------------------
// ConstraintViolationLoss: build x, sparse Ax via edge scatter, violation
// reduction to 4 scalars: [penalty, mean_viol, max_viol, n_violated].
// ---------------------------------------------------------------------------

// x[idx[i]] = src[i]
__global__ void k_scatter(const float* __restrict__ src, const int* __restrict__ idx,
                          float* __restrict__ x, int n) {
    int i = blockIdx.x * blockDim.x + threadIdx.x;
    if (i < n) x[idx[i]] = src[i];
}

// x[idx[i]] = softmax(logits[i,:]) @ [0..15] + offs[i]   (C fixed at 16)
__global__ void k_small_int(const float* __restrict__ logits, const float* __restrict__ offs,
                            const int* __restrict__ idx, float* __restrict__ x, int n) {
    int i = blockIdx.x * blockDim.x + threadIdx.x;
    if (i >= n) return;
    const float4* lp = reinterpret_cast<const float4*>(logits + (size_t)i * 16);
    float4 v0 = lp[0], v1 = lp[1], v2 = lp[2], v3 = lp[3];
    float l[16] = {v0.x, v0.y, v0.z, v0.w, v1.x, v1.y, v1.z, v1.w,
                   v2.x, v2.y, v2.z, v2.w, v3.x, v3.y, v3.z, v3.w};
    float m = l[0];
#pragma unroll
    for (int j = 1; j < 16; ++j) m = fmaxf(m, l[j]);
    float s = 0.f, ws = 0.f;
#pragma unroll
    for (int j = 0; j < 16; ++j) {
        float e = expf(l[j] - m);
        s += e;
        ws += e * (float)j;
    }
    x[idx[i]] = ws / s + offs[i];
}

// continuous vars (var_types==0) take variable_features[:, 8]
__global__ void k_continuous(const int* __restrict__ vt, const float* __restrict__ vf,
                             float* __restrict__ x, int n) {
    int v = blockIdx.x * blockDim.x + threadIdx.x;
    if (v < n && vt[v] == 0) x[v] = vf[(size_t)v * 16 + 8];
}

// Ax[row[e]] += ef[e] * x[col[e]]  (4 edges/thread, grid-stride)
__global__ void k_edges(const float* __restrict__ ef, const int* __restrict__ rows,
                        const int* __restrict__ cols, const float* __restrict__ x,
                        float* __restrict__ Ax, int e4, int E) {
    int stride = gridDim.x * blockDim.x;
    int gid = blockIdx.x * blockDim.x + threadIdx.x;
    for (int i = gid; i < e4; i += stride) {
        float4 f = reinterpret_cast<const float4*>(ef)[i];
        int4 r = reinterpret_cast<const int4*>(rows)[i];
        int4 c = reinterpret_cast<const int4*>(cols)[i];
        atomicAdd(&Ax[r.x], f.x * x[c.x]);
        atomicAdd(&Ax[r.y], f.y * x[c.y]);
        atomicAdd(&Ax[r.z], f.z * x[c.z]);
        atomicAdd(&Ax[r.w], f.w * x[c.w]);
    }
    // scalar tail (E not divisible by 4)
    for (int e = e4 * 4 + gid; e < E; e += stride) {
        atomicAdd(&Ax[rows[e]], ef[e] * x[cols[e]]);
    }
}

// per-constraint relu(Ax - bias) -> {sum, max, count>1e-6} accumulators
__global__ void k_reduce(const float* __restrict__ Ax, const float* __restrict__ cf,
                         float* __restrict__ acc, int ncon) {
    float lsum = 0.f, lmax = 0.f;
    unsigned lcnt = 0;
    int stride = gridDim.x * blockDim.x;
    for (int c = blockIdx.x * blockDim.x + threadIdx.x; c < ncon; c += stride) {
        float v = Ax[c] - cf[(size_t)c * 8 + 1];
        v = v > 0.f ? v : 0.f;
        lsum += v;
        lmax = fmaxf(lmax, v);
        lcnt += (v > 1e-6f) ? 1u : 0u;
    }
    // wave-64 reduce
#pragma unroll
    for (int o = 32; o > 0; o >>= 1) {
        lsum += __shfl_down(lsum, o);
        lmax = fmaxf(lmax, __shfl_down(lmax, o));
        lcnt += __shfl_down(lcnt, o);
    }
    __shared__ float ssum[4];
    __shared__ float smax[4];
    __shared__ unsigned scnt[4];
    int lane = threadIdx.x & 63, wid = threadIdx.x >> 6;
    if (lane == 0) { ssum[wid] = lsum; smax[wid] = lmax; scnt[wid] = lcnt; }
    __syncthreads();
    if (threadIdx.x == 0) {
        float bs = 0.f, bm = 0.f;
        unsigned bc = 0;
        int nw = (blockDim.x + 63) >> 6;
        for (int w = 0; w < nw; ++w) { bs += ssum[w]; bm = fmaxf(bm, smax[w]); bc += scnt[w]; }
        atomicAdd(&acc[0], bs);
        // violation >= 0, so float bits compare as unsigned
        atomicMax(reinterpret_cast<unsigned*>(acc) + 1, __float_as_uint(bm));
        atomicAdd(reinterpret_cast<unsigned*>(acc) + 2, bc);
    }
}

__global__ void k_final(const float* __restrict__ acc, float* __restrict__ out, int ncon) {
    if (blockIdx.x == 0 && threadIdx.x == 0) {
        float sum = acc[0];
        float mx = __uint_as_float(reinterpret_cast<const unsigned*>(acc)[1]);
        unsigned cnt = reinterpret_cast<const unsigned*>(acc)[2];
        float mean = sum / (float)ncon;
        out[0] = mean + 0.1f * mx;  // penalty = 1.0*mean + 0.1*max
        out[1] = mean;
        out[2] = mx;
        out[3] = (float)cnt;
    }
}

extern "C" void kernel_launch(void* const* d_in, const int* in_sizes, int n_in,
                              void* d_out, int out_size, void* d_ws, size_t ws_size,
                              hipStream_t stream) {
    const float* prob_bin       = (const float*)d_in[0];   // [NB]
    const float* logits_small   = (const float*)d_in[1];   // [NS,16]
    const float* offs_small     = (const float*)d_in[2];   // [NS]
    const float* pred_large     = (const float*)d_in[3];   // [NL]
    const float* edge_feat      = (const float*)d_in[4];   // [E]
    const float* cons_feat      = (const float*)d_in[5];   // [N_CON,8]
    const float* var_feat       = (const float*)d_in[6];   // [N_VARS,16]
    const int*   idx_bin        = (const int*)d_in[7];     // [NB]
    const int*   idx_small      = (const int*)d_in[8];     // [NS]
    const int*   idx_large      = (const int*)d_in[9];     // [NL]
    const int*   var_types      = (const int*)d_in[10];    // [N_VARS]
    const int*   edge_indices   = (const int*)d_in[11];    // [2,E]

    const int NB    = in_sizes[0];
    const int NS    = in_sizes[2];
    const int NL    = in_sizes[3];
    const int E     = in_sizes[4];
    const int NCON  = in_sizes[5] / 8;
    const int NVARS = in_sizes[10];

    const int* rows = edge_indices;
    const int* cols = edge_indices + E;

    float* x   = (float*)d_ws;            // [NVARS]
    float* Ax  = x + NVARS;               // [NCON]
    float* acc = Ax + NCON;               // [4]: sum, maxbits, count, pad

    // zero Ax + accumulators (ws is poisoned once, never re-poisoned)
    hipMemsetAsync(Ax, 0, (size_t)(NCON + 4) * sizeof(float), stream);

    const int B = 256;
    k_scatter<<<(NB + B - 1) / B, B, 0, stream>>>(prob_bin, idx_bin, x, NB);
    k_small_int<<<(NS + B - 1) / B, B, 0, stream>>>(logits_small, offs_small, idx_small, x, NS);
    k_scatter<<<(NL + B - 1) / B, B, 0, stream>>>(pred_large, idx_large, x, NL);
    k_continuous<<<(NVARS + B - 1) / B, B, 0, stream>>>(var_types, var_feat, x, NVARS);

    int e4 = E / 4;
    int edge_blocks = 2048;
    k_edges<<<edge_blocks, B, 0, stream>>>(edge_feat, rows, cols, x, Ax, e4, E);

    k_reduce<<<1024, B, 0, stream>>>(Ax, cons_feat, acc, NCON);
    k_final<<<1, 64, 0, stream>>>(acc, (float*)d_out, NCON);
}

// Round 2
// 685.748 us; speedup vs baseline: 1.2378x; 1.2378x over previous
//
#include <hip/hip_runtime.h>

// ---------------------------------------------------------------------------
// ConstraintViolationLoss: build x, sparse Ax via bucketed counting-sort +
// LDS accumulation (replaces 16M random memory-side atomics), then violation
// reduction to 4 scalars: [penalty, mean_viol, max_viol, n_violated].
// ---------------------------------------------------------------------------

#define BSHIFT 13
#define BROWS  (1 << BSHIFT)   // 8192 rows per bucket -> 32KB LDS tile
#define NBUCK_MAX 64
#define CHUNK 4096             // edges per partition block
#define EPT   (CHUNK / 256)    // 16 edges per thread
#define SPLIT 8                // blocks per bucket in accumulate

// ------------------------------ build x ------------------------------------

__global__ void k_scatter(const float* __restrict__ src, const int* __restrict__ idx,
                          float* __restrict__ x, int n) {
    int i = blockIdx.x * blockDim.x + threadIdx.x;
    if (i < n) x[idx[i]] = src[i];
}

__global__ void k_small_int(const float* __restrict__ logits, const float* __restrict__ offs,
                            const int* __restrict__ idx, float* __restrict__ x, int n) {
    int i = blockIdx.x * blockDim.x + threadIdx.x;
    if (i >= n) return;
    const float4* lp = reinterpret_cast<const float4*>(logits + (size_t)i * 16);
    float4 v0 = lp[0], v1 = lp[1], v2 = lp[2], v3 = lp[3];
    float l[16] = {v0.x, v0.y, v0.z, v0.w, v1.x, v1.y, v1.z, v1.w,
                   v2.x, v2.y, v2.z, v2.w, v3.x, v3.y, v3.z, v3.w};
    float m = l[0];
#pragma unroll
    for (int j = 1; j < 16; ++j) m = fmaxf(m, l[j]);
    float s = 0.f, ws = 0.f;
#pragma unroll
    for (int j = 0; j < 16; ++j) {
        float e = expf(l[j] - m);
        s += e;
        ws += e * (float)j;
    }
    x[idx[i]] = ws / s + offs[i];
}

__global__ void k_continuous(const int* __restrict__ vt, const float* __restrict__ vf,
                             float* __restrict__ x, int n) {
    int v = blockIdx.x * blockDim.x + threadIdx.x;
    if (v < n && vt[v] == 0) x[v] = vf[(size_t)v * 16 + 8];
}

// ------------------------- bucketed segment-sum ----------------------------

// global histogram of edges per row-bucket (LDS-aggregated)
__global__ __launch_bounds__(256) void k_hist(const int* __restrict__ rows,
                                              int* __restrict__ bcount, int E, int nbuck) {
    __shared__ int h[NBUCK_MAX];
    for (int i = threadIdx.x; i < NBUCK_MAX; i += 256) h[i] = 0;
    __syncthreads();
    int stride = gridDim.x * blockDim.x;
    int gid = blockIdx.x * blockDim.x + threadIdx.x;
    int e4 = E >> 2;
    for (int i = gid; i < e4; i += stride) {
        int4 r = reinterpret_cast<const int4*>(rows)[i];
        atomicAdd(&h[r.x >> BSHIFT], 1);
        atomicAdd(&h[r.y >> BSHIFT], 1);
        atomicAdd(&h[r.z >> BSHIFT], 1);
        atomicAdd(&h[r.w >> BSHIFT], 1);
    }
    for (int e = (e4 << 2) + gid; e < E; e += stride)
        atomicAdd(&h[rows[e] >> BSHIFT], 1);
    __syncthreads();
    for (int i = threadIdx.x; i < nbuck; i += 256)
        if (h[i]) atomicAdd(&bcount[i], h[i]);
}

// exclusive scan of 62 counters (trivial single-thread)
__global__ void k_scan(const int* __restrict__ bcount, int* __restrict__ bbase,
                       int* __restrict__ bcur, int nbuck) {
    if (blockIdx.x == 0 && threadIdx.x == 0) {
        int s = 0;
        for (int i = 0; i < nbuck; ++i) {
            bbase[i] = s;
            bcur[i]  = s;
            s += bcount[i];
        }
        bbase[nbuck] = s;
    }
}

// partition: write val = ef*x[col] and row_local into bucket-sorted arrays
__global__ __launch_bounds__(256) void k_part(const int* __restrict__ rows,
                                              const int* __restrict__ cols,
                                              const float* __restrict__ ef,
                                              const float* __restrict__ x,
                                              int* __restrict__ bcur,
                                              float* __restrict__ vals,
                                              unsigned short* __restrict__ locs,
                                              int E, int nbuck) {
    __shared__ int h[NBUCK_MAX];
    __shared__ int gcur[NBUCK_MAX];
    const int base = blockIdx.x * CHUNK;
    for (int i = threadIdx.x; i < NBUCK_MAX; i += 256) h[i] = 0;
    __syncthreads();
    int rr[EPT];
#pragma unroll
    for (int k = 0; k < EPT; ++k) {
        int e = base + threadIdx.x + k * 256;
        int r = (e < E) ? rows[e] : -1;
        rr[k] = r;
        if (r >= 0) atomicAdd(&h[r >> BSHIFT], 1);
    }
    __syncthreads();
    if (threadIdx.x < nbuck)
        gcur[threadIdx.x] = atomicAdd(&bcur[threadIdx.x], h[threadIdx.x]);
    __syncthreads();
#pragma unroll
    for (int k = 0; k < EPT; ++k) {
        int e = base + threadIdx.x + k * 256;
        int r = rr[k];
        if (r >= 0) {
            float v = ef[e] * x[cols[e]];
            int slot = atomicAdd(&gcur[r >> BSHIFT], 1);
            vals[slot] = v;
            locs[slot] = (unsigned short)(r & (BROWS - 1));
        }
    }
}

// accumulate one bucket slice in LDS, flush with contiguous atomics
__global__ __launch_bounds__(256) void k_accum(const float* __restrict__ vals,
                                               const unsigned short* __restrict__ locs,
                                               const int* __restrict__ bbase,
                                               float* __restrict__ Ax, int ncon) {
    __shared__ float ax[BROWS];
    int b = blockIdx.x / SPLIT, s = blockIdx.x % SPLIT;
    for (int i = threadIdx.x; i < BROWS; i += 256) ax[i] = 0.f;
    __syncthreads();
    int lo = bbase[b], hi = bbase[b + 1];
    int len = hi - lo;
    int per = (len + SPLIT - 1) / SPLIT;
    int s0 = lo + s * per;
    int s1 = s0 + per; if (s1 > hi) s1 = hi;
    for (int i = s0 + threadIdx.x; i < s1; i += 256)
        atomicAdd(&ax[locs[i]], vals[i]);
    __syncthreads();
    int rowbase = b << BSHIFT;
    for (int i = threadIdx.x; i < BROWS; i += 256) {
        int r = rowbase + i;
        float v = ax[i];
        if (r < ncon && v != 0.f) atomicAdd(&Ax[r], v);
    }
}

// fallback: direct random atomics (used only if ws too small)
__global__ void k_edges(const float* __restrict__ ef, const int* __restrict__ rows,
                        const int* __restrict__ cols, const float* __restrict__ x,
                        float* __restrict__ Ax, int e4, int E) {
    int stride = gridDim.x * blockDim.x;
    int gid = blockIdx.x * blockDim.x + threadIdx.x;
    for (int i = gid; i < e4; i += stride) {
        float4 f = reinterpret_cast<const float4*>(ef)[i];
        int4 r = reinterpret_cast<const int4*>(rows)[i];
        int4 c = reinterpret_cast<const int4*>(cols)[i];
        atomicAdd(&Ax[r.x], f.x * x[c.x]);
        atomicAdd(&Ax[r.y], f.y * x[c.y]);
        atomicAdd(&Ax[r.z], f.z * x[c.z]);
        atomicAdd(&Ax[r.w], f.w * x[c.w]);
    }
    for (int e = e4 * 4 + gid; e < E; e += stride)
        atomicAdd(&Ax[rows[e]], ef[e] * x[cols[e]]);
}

// ------------------------------ reduction ----------------------------------

__global__ void k_reduce(const float* __restrict__ Ax, const float* __restrict__ cf,
                         float* __restrict__ acc, int ncon) {
    float lsum = 0.f, lmax = 0.f;
    unsigned lcnt = 0;
    int stride = gridDim.x * blockDim.x;
    for (int c = blockIdx.x * blockDim.x + threadIdx.x; c < ncon; c += stride) {
        float v = Ax[c] - cf[(size_t)c * 8 + 1];
        v = v > 0.f ? v : 0.f;
        lsum += v;
        lmax = fmaxf(lmax, v);
        lcnt += (v > 1e-6f) ? 1u : 0u;
    }
#pragma unroll
    for (int o = 32; o > 0; o >>= 1) {
        lsum += __shfl_down(lsum, o);
        lmax = fmaxf(lmax, __shfl_down(lmax, o));
        lcnt += __shfl_down(lcnt, o);
    }
    __shared__ float ssum[4];
    __shared__ float smax[4];
    __shared__ unsigned scnt[4];
    int lane = threadIdx.x & 63, wid = threadIdx.x >> 6;
    if (lane == 0) { ssum[wid] = lsum; smax[wid] = lmax; scnt[wid] = lcnt; }
    __syncthreads();
    if (threadIdx.x == 0) {
        float bs = 0.f, bm = 0.f;
        unsigned bc = 0;
        int nw = (blockDim.x + 63) >> 6;
        for (int w = 0; w < nw; ++w) { bs += ssum[w]; bm = fmaxf(bm, smax[w]); bc += scnt[w]; }
        atomicAdd(&acc[0], bs);
        atomicMax(reinterpret_cast<unsigned*>(acc) + 1, __float_as_uint(bm));
        atomicAdd(reinterpret_cast<unsigned*>(acc) + 2, bc);
    }
}

__global__ void k_final(const float* __restrict__ acc, float* __restrict__ out, int ncon) {
    if (blockIdx.x == 0 && threadIdx.x == 0) {
        float sum = acc[0];
        float mx = __uint_as_float(reinterpret_cast<const unsigned*>(acc)[1]);
        unsigned cnt = reinterpret_cast<const unsigned*>(acc)[2];
        float mean = sum / (float)ncon;
        out[0] = mean + 0.1f * mx;
        out[1] = mean;
        out[2] = mx;
        out[3] = (float)cnt;
    }
}

// ------------------------------ launcher -----------------------------------

extern "C" void kernel_launch(void* const* d_in, const int* in_sizes, int n_in,
                              void* d_out, int out_size, void* d_ws, size_t ws_size,
                              hipStream_t stream) {
    const float* prob_bin     = (const float*)d_in[0];
    const float* logits_small = (const float*)d_in[1];
    const float* offs_small   = (const float*)d_in[2];
    const float* pred_large   = (const float*)d_in[3];
    const float* edge_feat    = (const float*)d_in[4];
    const float* cons_feat    = (const float*)d_in[5];
    const float* var_feat     = (const float*)d_in[6];
    const int*   idx_bin      = (const int*)d_in[7];
    const int*   idx_small    = (const int*)d_in[8];
    const int*   idx_large    = (const int*)d_in[9];
    const int*   var_types    = (const int*)d_in[10];
    const int*   edge_indices = (const int*)d_in[11];

    const int NB    = in_sizes[0];
    const int NS    = in_sizes[2];
    const int NL    = in_sizes[3];
    const int E     = in_sizes[4];
    const int NCON  = in_sizes[5] / 8;
    const int NVARS = in_sizes[10];

    const int* rows = edge_indices;
    const int* cols = edge_indices + E;

    const int NBUCK = (NCON + BROWS - 1) >> BSHIFT;

    // ws layout: x | Ax | acc[4] | bcount | bbase[+1] | bcur | vals | locs
    float* x   = (float*)d_ws;
    float* Ax  = x + NVARS;
    float* acc = Ax + NCON;
    int*   bcount = (int*)(acc + 4);
    int*   bbase  = bcount + NBUCK;
    int*   bcur   = bbase + NBUCK + 1;
    float* vals   = (float*)(bcur + NBUCK);
    unsigned short* locs = (unsigned short*)(vals + E);

    size_t need = (size_t)(NVARS + NCON + 4 + 3 * NBUCK + 1) * 4
                + (size_t)E * 4 + (size_t)E * 2;
    bool sorted_path = (ws_size >= need) && (NBUCK <= NBUCK_MAX);

    const int B = 256;

    // zero Ax + acc + counters in one memset
    hipMemsetAsync(Ax, 0, (size_t)(NCON + 4 + 3 * NBUCK + 1) * sizeof(float), stream);

    k_scatter<<<(NB + B - 1) / B, B, 0, stream>>>(prob_bin, idx_bin, x, NB);
    k_small_int<<<(NS + B - 1) / B, B, 0, stream>>>(logits_small, offs_small, idx_small, x, NS);
    k_scatter<<<(NL + B - 1) / B, B, 0, stream>>>(pred_large, idx_large, x, NL);
    k_continuous<<<(NVARS + B - 1) / B, B, 0, stream>>>(var_types, var_feat, x, NVARS);

    if (sorted_path) {
        k_hist<<<2048, B, 0, stream>>>(rows, bcount, E, NBUCK);
        k_scan<<<1, 64, 0, stream>>>(bcount, bbase, bcur, NBUCK);
        int nchunks = (E + CHUNK - 1) / CHUNK;
        k_part<<<nchunks, B, 0, stream>>>(rows, cols, edge_feat, x, bcur, vals, locs, E, NBUCK);
        k_accum<<<NBUCK * SPLIT, B, 0, stream>>>(vals, locs, bbase, Ax, NCON);
    } else {
        int e4 = E / 4;
        k_edges<<<2048, B, 0, stream>>>(edge_feat, rows, cols, x, Ax, e4, E);
    }

    k_reduce<<<1024, B, 0, stream>>>(Ax, cons_feat, acc, NCON);
    k_final<<<1, 64, 0, stream>>>(acc, (float*)d_out, NCON);
}